// Round 7
// baseline (474.941 us; speedup 1.0000x reference)
//
#include <hip/hip_runtime.h>
#include <math.h>

#define NN 100000
#define NE 1600000
#define NB 391          // ceil(NN/256) buckets of 256 dst nodes
#define BKSH 8
#define EPB 6250        // NE / 256 blocks
#define CSTAGE 5120     // LDS staging entries in bktcsr (mean 4096, +16 sigma)
#define NDEG 64         // degree clamp for balance sort
#define DTOT (NDEG * NB)

typedef __attribute__((ext_vector_type(8))) short bf16x8;
typedef __attribute__((ext_vector_type(4))) float f32x4;

// ---------------------------------------------------------------- bf16 utils
__device__ __forceinline__ unsigned short f2bf(float x) {
  unsigned int u = __float_as_uint(x);
  u += 0x7fffu + ((u >> 16) & 1u);   // RNE
  return (unsigned short)(u >> 16);
}
__device__ __forceinline__ float bf2f(unsigned short b) {
  return __uint_as_float(((unsigned int)b) << 16);
}
__device__ __forceinline__ void unpack8(uint4 u, float* f) {
  f[0] = __uint_as_float(u.x << 16); f[1] = __uint_as_float(u.x & 0xffff0000u);
  f[2] = __uint_as_float(u.y << 16); f[3] = __uint_as_float(u.y & 0xffff0000u);
  f[4] = __uint_as_float(u.z << 16); f[5] = __uint_as_float(u.z & 0xffff0000u);
  f[6] = __uint_as_float(u.w << 16); f[7] = __uint_as_float(u.w & 0xffff0000u);
}
__device__ __forceinline__ void split8(const float* f, bf16x8& h8, bf16x8& l8) {
  union { bf16x8 v; unsigned short s[8]; } H, L;
  #pragma unroll
  for (int j = 0; j < 8; ++j) {
    const unsigned short hh = f2bf(f[j]);
    H.s[j] = hh;
    L.s[j] = f2bf(f[j] - bf2f(hh));
  }
  h8 = H.v; l8 = L.v;
}
__device__ __forceinline__ void gl_lds16(const void* g, void* lds) {
  __builtin_amdgcn_global_load_lds(
      (const __attribute__((address_space(1))) unsigned int*)g,
      (__attribute__((address_space(3))) unsigned int*)lds, 16, 0, 0);
}

// counted-vmcnt pipeline barriers (T3/T4 minimal form): pf(s+1)=16 newest
// loads stay in flight; vmcnt(16) guarantees pf(s) landed; raw s_barrier
// publishes all waves' pf writes. "memory" clobber pins ordering.
#define PIPE_WAIT16 asm volatile("s_waitcnt vmcnt(16)\n\ts_barrier" ::: "memory")
#define PIPE_WAIT0  asm volatile("s_waitcnt vmcnt(0)\n\ts_barrier" ::: "memory")
#define PIPE_BAR    asm volatile("s_barrier" ::: "memory")

// ---------------------------------------------------------------- CSR build (bucketed)
__global__ __launch_bounds__(256)
void bktcnt_k(const int* __restrict__ dst, int* __restrict__ gcnt) {
  __shared__ int cnt[NB];
  for (int i = threadIdx.x; i < NB; i += 256) cnt[i] = 0;
  __syncthreads();
  const int e0 = blockIdx.x * EPB;
  for (int e = e0 + threadIdx.x; e < e0 + EPB; e += 256)
    atomicAdd(&cnt[dst[e] >> BKSH], 1);
  __syncthreads();
  for (int i = threadIdx.x; i < NB; i += 256)
    if (cnt[i]) atomicAdd(&gcnt[i], cnt[i]);
}

__global__ void bktscan_k(const int* __restrict__ gcnt, int* __restrict__ base,
                          int* __restrict__ cursor) {
  __shared__ int sh[512];
  const int t = threadIdx.x;
  const int v = (t < NB) ? gcnt[t] : 0;
  sh[t] = v;
  __syncthreads();
  #pragma unroll
  for (int off = 1; off < 512; off <<= 1) {
    int nv = (t >= off) ? sh[t - off] : 0;
    __syncthreads();
    sh[t] += nv;
    __syncthreads();
  }
  const int excl = sh[t] - v;
  if (t < NB) { base[t] = excl; cursor[t] = excl; }
  if (t == NB - 1) base[NB] = excl + v;   // == NE
}

__global__ __launch_bounds__(256)
void bktscat_k(const int* __restrict__ src, const int* __restrict__ dst,
               int* __restrict__ cursor, unsigned int* __restrict__ pairs) {
  __shared__ int cnt[NB];
  __shared__ int bbase[NB];
  for (int i = threadIdx.x; i < NB; i += 256) cnt[i] = 0;
  __syncthreads();
  const int e0 = blockIdx.x * EPB;
  for (int e = e0 + threadIdx.x; e < e0 + EPB; e += 256)
    atomicAdd(&cnt[dst[e] >> BKSH], 1);
  __syncthreads();
  for (int i = threadIdx.x; i < NB; i += 256) {
    bbase[i] = cnt[i] ? atomicAdd(&cursor[i], cnt[i]) : 0;
    cnt[i] = 0;
  }
  __syncthreads();
  for (int e = e0 + threadIdx.x; e < e0 + EPB; e += 256) {
    const int d = dst[e];
    const int b = d >> BKSH;
    const int loc = atomicAdd(&cnt[b], 1);
    pairs[bbase[b] + loc] = ((unsigned)src[e] << BKSH) | (unsigned)(d & 255);
  }
}

__global__ __launch_bounds__(256)
void bktcsr_k(const unsigned int* __restrict__ pairs, const int* __restrict__ base,
              int* __restrict__ rowp, int* __restrict__ cidx) {
  __shared__ int cnt[256];
  __shared__ int sums[256];
  __shared__ int stage[CSTAGE];
  const int b = blockIdx.x, t = threadIdx.x;
  const int p0 = base[b], p1 = base[b + 1], bs = p1 - p0;
  const int n0 = b << BKSH;
  const int nloc = (NN - n0 < 256) ? (NN - n0) : 256;
  cnt[t] = 0;
  __syncthreads();
  for (int i = p0 + t; i < p1; i += 256)
    atomicAdd(&cnt[pairs[i] & 255], 1);
  __syncthreads();
  const int v = cnt[t];
  sums[t] = v;
  __syncthreads();
  #pragma unroll
  for (int off = 1; off < 256; off <<= 1) {
    int nv = (t >= off) ? sums[t - off] : 0;
    __syncthreads();
    sums[t] += nv;
    __syncthreads();
  }
  const int myexcl = sums[t] - v;
  if (t < nloc) rowp[n0 + t] = p0 + myexcl;
  if (b == 0 && t == 0) rowp[NN] = base[NB];
  __syncthreads();
  cnt[t] = myexcl;     // reuse as cursor
  __syncthreads();
  if (bs <= CSTAGE) {
    for (int i = p0 + t; i < p1; i += 256) {
      const unsigned pk = pairs[i];
      const int loc = atomicAdd(&cnt[pk & 255], 1);
      stage[loc] = (int)(pk >> BKSH);
    }
    __syncthreads();
    for (int i = t; i < bs; i += 256) cidx[p0 + i] = stage[i];
  } else {
    for (int i = p0 + t; i < p1; i += 256) {
      const unsigned pk = pairs[i];
      const int loc = atomicAdd(&cnt[pk & 255], 1);
      cidx[p0 + loc] = (int)(pk >> BKSH);
    }
  }
}

// ---------------------------------------------------------------- degree sort
__global__ __launch_bounds__(256)
void dcnt_k(const int* __restrict__ rowp, int* __restrict__ gdcnt) {
  __shared__ int h[NDEG];
  const int t = threadIdx.x, b = blockIdx.x;
  if (t < NDEG) h[t] = 0;
  __syncthreads();
  const int n = b * 256 + t;
  if (n < NN) {
    int d = rowp[n + 1] - rowp[n];
    if (d > NDEG - 1) d = NDEG - 1;
    atomicAdd(&h[d], 1);
  }
  __syncthreads();
  if (t < NDEG) gdcnt[t * NB + b] = h[t];
}

__global__ __launch_bounds__(1024)
void dscan2_k(int* __restrict__ g) {
  __shared__ int part[1024];
  const int t = threadIdx.x;
  constexpr int PER = (DTOT + 1023) / 1024;   // 25
  int vals[PER];
  const int base = t * PER;
  int sum = 0;
  #pragma unroll
  for (int i = 0; i < PER; ++i) {
    const int idx = base + i;
    const int v = (idx < DTOT) ? g[idx] : 0;
    vals[i] = sum;
    sum += v;
  }
  part[t] = sum;
  __syncthreads();
  #pragma unroll
  for (int off = 1; off < 1024; off <<= 1) {
    int nv = (t >= off) ? part[t - off] : 0;
    __syncthreads();
    part[t] += nv;
    __syncthreads();
  }
  const int excl = part[t] - sum;
  #pragma unroll
  for (int i = 0; i < PER; ++i) {
    const int idx = base + i;
    if (idx < DTOT) g[idx] = excl + vals[i];
  }
}

__global__ __launch_bounds__(256)
void dperm2_k(const int* __restrict__ rowp, const int* __restrict__ gdcnt,
              int* __restrict__ perm) {
  __shared__ int lcur[NDEG];
  const int t = threadIdx.x, b = blockIdx.x;
  if (t < NDEG) lcur[t] = 0;
  __syncthreads();
  const int n = b * 256 + t;
  if (n < NN) {
    int d = rowp[n + 1] - rowp[n];
    if (d > NDEG - 1) d = NDEG - 1;
    const int r = atomicAdd(&lcur[d], 1);   // LDS-only atomic
    perm[gdcnt[d * NB + b] + r] = n;
  }
}

// ---------------------------------------------------------------- W convert
struct WConv { const float* src; unsigned short* hi; unsigned short* lo; int dout; };
struct WConv8 { WConv m[8]; };

__global__ void wconv_k(WConv8 a) {
  const WConv w = a.m[blockIdx.x];
  const int n = 128 * w.dout;
  for (int i = threadIdx.x; i < n; i += blockDim.x) {
    const int c = i >> 7, kk = i & 127;  // out idx = c*128 + kk
    const float x = w.src[(size_t)kk * w.dout + c];
    const unsigned short h = f2bf(x);
    w.hi[i] = h;
    w.lo[i] = f2bf(x - bf2f(h));
  }
}

// ---------------------------------------------------------------- GEMM x4 (MFMA)
// Counted-vmcnt double-buffer: prefetch stays in flight across the barrier.
struct GMat { const unsigned short* wh; const unsigned short* wl;
              const float* bias; float* outf; unsigned short* outb; };
struct GArgs { GMat m[4]; };

template <int DOUT, bool PRESPLIT>
__global__ __launch_bounds__(256, 3)
void gemm4_mfma(const float* __restrict__ X,
                const unsigned short* __restrict__ Xh,
                const unsigned short* __restrict__ Xl,
                int nrows, GArgs ga) {
  constexpr int NCG = DOUT / 64;
  constexpr int NS = 4 * NCG * 2;
  __shared__ __align__(16) unsigned short Bs[2][8192];
  const int t = threadIdx.x;
  const int w = t >> 6, l = t & 63;
  const int lr = l & 15, lg = l >> 4;
  const int row0 = blockIdx.x * 128;

  bf16x8 ah[2][4], al[2][4];
  #pragma unroll
  for (int rf = 0; rf < 2; ++rf) {
    const int r = row0 + w * 32 + rf * 16 + lr;
    const bool ok = r < nrows;
    if constexpr (!PRESPLIT) {
      const float* xp = &X[(size_t)r * 128];
      #pragma unroll
      for (int ks = 0; ks < 4; ++ks) {
        float f[8];
        if (ok) {
          *(float4*)&f[0] = *(const float4*)&xp[ks * 32 + lg * 8];
          *(float4*)&f[4] = *(const float4*)&xp[ks * 32 + lg * 8 + 4];
        } else {
          #pragma unroll
          for (int j = 0; j < 8; ++j) f[j] = 0.f;
        }
        split8(f, ah[rf][ks], al[rf][ks]);
      }
    } else {
      #pragma unroll
      for (int ks = 0; ks < 4; ++ks) {
        if (ok) {
          ah[rf][ks] = *(const bf16x8*)&Xh[(size_t)r * 128 + ks * 32 + lg * 8];
          al[rf][ks] = *(const bf16x8*)&Xl[(size_t)r * 128 + ks * 32 + lg * 8];
        } else {
          union { bf16x8 v; unsigned short s[8]; } z;
          #pragma unroll
          for (int j = 0; j < 8; ++j) z.s[j] = 0;
          ah[rf][ks] = z.v; al[rf][ks] = z.v;
        }
      }
    }
  }

  auto stage = [&](int buf, int s) {
    const int m = s / (NCG * 2);
    const int rem = s - m * (NCG * 2);
    const int cg = rem >> 1, pl = rem & 1;
    const char* gb = (const char*)((pl ? ga.m[m].wl : ga.m[m].wh) + cg * 64 * 128);
    char* lb = (char*)&Bs[buf][0];
    #pragma unroll
    for (int i = 0; i < 4; ++i) {
      const int seg = (w * 4 + i) << 10;
      const int o = seg + l * 16;
      const int osw = o ^ (((o >> 8) & 7) << 4);
      gl_lds16(gb + osw, lb + seg);
    }
  };

  f32x4 acc[4][2];
  stage(0, 0);          // 16 loads/wave in flight
  int cur = 0;
  const int sw = (lr & 7) << 4;
  for (int s = 0; s < NS; ++s) {
    if (s + 1 < NS) {
      stage(cur ^ 1, s + 1);   // 16 newest loads
      PIPE_WAIT16;             // pf(s) landed (all waves after barrier)
    } else {
      PIPE_WAIT0;              // last stage: drain
    }
    const int m = s / (NCG * 2);
    const int rem = s - m * (NCG * 2);
    const int cg = rem >> 1, pl = rem & 1;
    const char* lbase = (const char*)&Bs[cur][0];
    if (pl == 0) {
      #pragma unroll
      for (int nf = 0; nf < 4; ++nf) {
        const char* lp = lbase + nf * 4096 + lr * 256;
        bf16x8 bq[4];
        #pragma unroll
        for (int ks = 0; ks < 4; ++ks)
          bq[ks] = *(const bf16x8*)(lp + (((ks * 64 + lg * 16) ^ sw)));
        f32x4 a0 = {0.f, 0.f, 0.f, 0.f}, a1 = a0;
        #pragma unroll
        for (int ks = 0; ks < 4; ++ks) {
          a0 = __builtin_amdgcn_mfma_f32_16x16x32_bf16(ah[0][ks], bq[ks], a0, 0, 0, 0);
          a1 = __builtin_amdgcn_mfma_f32_16x16x32_bf16(ah[1][ks], bq[ks], a1, 0, 0, 0);
        }
        #pragma unroll
        for (int ks = 0; ks < 4; ++ks) {
          a0 = __builtin_amdgcn_mfma_f32_16x16x32_bf16(al[0][ks], bq[ks], a0, 0, 0, 0);
          a1 = __builtin_amdgcn_mfma_f32_16x16x32_bf16(al[1][ks], bq[ks], a1, 0, 0, 0);
        }
        acc[nf][0] = a0; acc[nf][1] = a1;
      }
    } else {
      const GMat gm = ga.m[m];
      #pragma unroll
      for (int nf = 0; nf < 4; ++nf) {
        const char* lp = lbase + nf * 4096 + lr * 256;
        bf16x8 bq[4];
        #pragma unroll
        for (int ks = 0; ks < 4; ++ks)
          bq[ks] = *(const bf16x8*)(lp + (((ks * 64 + lg * 16) ^ sw)));
        f32x4 a0 = acc[nf][0], a1 = acc[nf][1];
        #pragma unroll
        for (int ks = 0; ks < 4; ++ks) {
          a0 = __builtin_amdgcn_mfma_f32_16x16x32_bf16(ah[0][ks], bq[ks], a0, 0, 0, 0);
          a1 = __builtin_amdgcn_mfma_f32_16x16x32_bf16(ah[1][ks], bq[ks], a1, 0, 0, 0);
        }
        const int col = cg * 64 + nf * 16 + lr;
        const float bb = gm.bias[col];
        #pragma unroll
        for (int j = 0; j < 4; ++j) {
          const int r0 = row0 + w * 32 + lg * 4 + j;
          const int r1 = r0 + 16;
          if (gm.outb) {
            if (r0 < nrows) gm.outb[(size_t)r0 * DOUT + col] = f2bf(a0[j] + bb);
            if (r1 < nrows) gm.outb[(size_t)r1 * DOUT + col] = f2bf(a1[j] + bb);
          } else {
            if (r0 < nrows) gm.outf[(size_t)r0 * DOUT + col] = a0[j] + bb;
            if (r1 < nrows) gm.outf[(size_t)r1 * DOUT + col] = a1[j] + bb;
          }
        }
      }
    }
    if (s + 1 < NS) PIPE_BAR;   // close reads of buf cur before pf(s+2) overwrites
    cur ^= 1;
  }
}

// ---------------------------------------------------------------- attention
// Layer 1: heads=8, C=16, concat. 8 lanes/node, 4-edge deep pipeline.
__global__ __launch_bounds__(256)
void attn1_k(const unsigned short* __restrict__ q, const unsigned short* __restrict__ k,
             const unsigned short* __restrict__ v, const float* __restrict__ skip,
             const int* __restrict__ rowp, const int* __restrict__ cidx,
             const int* __restrict__ perm,
             unsigned short* __restrict__ hhi, unsigned short* __restrict__ hlo) {
  const int idx = blockIdx.x * 32 + (threadIdx.x >> 3);
  if (idx >= NN) return;
  const int node = perm[idx];
  const int cb = (threadIdx.x & 7) * 16;
  float qv[16];
  {
    uint4 q0 = *(const uint4*)&q[(size_t)node * 128 + cb];
    uint4 q1 = *(const uint4*)&q[(size_t)node * 128 + cb + 8];
    unpack8(q0, qv); unpack8(q1, qv + 8);
    #pragma unroll
    for (int c = 0; c < 16; ++c) qv[c] *= 0.25f;  // 1/sqrt(16)
  }
  float s = 0.f, acc[16];
  #pragma unroll
  for (int c = 0; c < 16; ++c) acc[c] = 0.f;
  const int e0 = rowp[node], e1 = rowp[node + 1];
  int e = e0;
  for (; e + 3 < e1; e += 4) {
    int sidx[4];
    #pragma unroll
    for (int j = 0; j < 4; ++j) sidx[j] = cidx[e + j];
    uint4 K[4][2], V[4][2];
    #pragma unroll
    for (int j = 0; j < 4; ++j) {
      const size_t o = (size_t)sidx[j] * 128 + cb;
      K[j][0] = *(const uint4*)&k[o];
      K[j][1] = *(const uint4*)&k[o + 8];
      V[j][0] = *(const uint4*)&v[o];
      V[j][1] = *(const uint4*)&v[o + 8];
    }
    float pr[4];
    #pragma unroll
    for (int j = 0; j < 4; ++j) {
      float kv[16];
      unpack8(K[j][0], kv); unpack8(K[j][1], kv + 8);
      float d = 0.f;
      #pragma unroll
      for (int c = 0; c < 16; ++c) d = fmaf(qv[c], kv[c], d);
      pr[j] = __expf(d);
      s += pr[j];
    }
    #pragma unroll
    for (int j = 0; j < 4; ++j) {
      float vv[16];
      unpack8(V[j][0], vv); unpack8(V[j][1], vv + 8);
      #pragma unroll
      for (int c = 0; c < 16; ++c) acc[c] = fmaf(pr[j], vv[c], acc[c]);
    }
  }
  for (; e < e1; ++e) {
    const int sa = cidx[e];
    uint4 k0 = *(const uint4*)&k[(size_t)sa * 128 + cb];
    uint4 k1 = *(const uint4*)&k[(size_t)sa * 128 + cb + 8];
    uint4 v0 = *(const uint4*)&v[(size_t)sa * 128 + cb];
    uint4 v1 = *(const uint4*)&v[(size_t)sa * 128 + cb + 8];
    float kv[16]; unpack8(k0, kv); unpack8(k1, kv + 8);
    float d = 0.f;
    #pragma unroll
    for (int c = 0; c < 16; ++c) d = fmaf(qv[c], kv[c], d);
    const float p = __expf(d);
    s += p;
    float vv[16]; unpack8(v0, vv); unpack8(v1, vv + 8);
    #pragma unroll
    for (int c = 0; c < 16; ++c) acc[c] = fmaf(p, vv[c], acc[c]);
  }
  const float inv = (e1 > e0) ? 1.f / s : 0.f;
  float sk[16];
  {
    const float* sp = &skip[(size_t)node * 128 + cb];
    *(float4*)&sk[0]  = *(const float4*)&sp[0];
    *(float4*)&sk[4]  = *(const float4*)&sp[4];
    *(float4*)&sk[8]  = *(const float4*)&sp[8];
    *(float4*)&sk[12] = *(const float4*)&sp[12];
  }
  unsigned int hw[8], lw[8];
  #pragma unroll
  for (int c2 = 0; c2 < 8; ++c2) {
    const float oa = fmaxf(fmaf(acc[2 * c2], inv, sk[2 * c2]), 0.f);
    const float ob = fmaxf(fmaf(acc[2 * c2 + 1], inv, sk[2 * c2 + 1]), 0.f);
    const unsigned short ha = f2bf(oa), hb = f2bf(ob);
    hw[c2] = (unsigned)ha | ((unsigned)hb << 16);
    lw[c2] = (unsigned)f2bf(oa - bf2f(ha)) | ((unsigned)f2bf(ob - bf2f(hb)) << 16);
  }
  uint4* HH = (uint4*)&hhi[(size_t)node * 128 + cb];
  uint4* LL = (uint4*)&hlo[(size_t)node * 128 + cb];
  HH[0] = make_uint4(hw[0], hw[1], hw[2], hw[3]);
  HH[1] = make_uint4(hw[4], hw[5], hw[6], hw[7]);
  LL[0] = make_uint4(lw[0], lw[1], lw[2], lw[3]);
  LL[1] = make_uint4(lw[4], lw[5], lw[6], lw[7]);
}

// Layer 2: heads=1, C=64. 8 lanes/node, 4-edge deep pipeline.
__global__ __launch_bounds__(256)
void attn2_k(const unsigned short* __restrict__ q, const unsigned short* __restrict__ k,
             const unsigned short* __restrict__ v, const float* __restrict__ skip,
             const int* __restrict__ rowp, const int* __restrict__ cidx,
             const int* __restrict__ perm, float* __restrict__ out) {
  const int idx = blockIdx.x * 32 + (threadIdx.x >> 3);
  if (idx >= NN) return;
  const int node = perm[idx];
  const int cb = (threadIdx.x & 7) * 8;
  float qv[8];
  {
    uint4 q0 = *(const uint4*)&q[(size_t)node * 64 + cb];
    unpack8(q0, qv);
    #pragma unroll
    for (int c = 0; c < 8; ++c) qv[c] *= 0.125f;  // 1/sqrt(64)
  }
  float s = 0.f, acc[8];
  #pragma unroll
  for (int c = 0; c < 8; ++c) acc[c] = 0.f;
  const int e0 = rowp[node], e1 = rowp[node + 1];
  int e = e0;
  for (; e + 3 < e1; e += 4) {
    int sidx[4];
    #pragma unroll
    for (int j = 0; j < 4; ++j) sidx[j] = cidx[e + j];
    uint4 K[4], V[4];
    #pragma unroll
    for (int j = 0; j < 4; ++j) {
      const size_t o = (size_t)sidx[j] * 64 + cb;
      K[j] = *(const uint4*)&k[o];
      V[j] = *(const uint4*)&v[o];
    }
    float dd[4];
    #pragma unroll
    for (int j = 0; j < 4; ++j) {
      float kv[8]; unpack8(K[j], kv);
      float d = 0.f;
      #pragma unroll
      for (int c = 0; c < 8; ++c) d = fmaf(qv[c], kv[c], d);
      dd[j] = d;
    }
    #pragma unroll
    for (int j = 0; j < 4; ++j) {
      dd[j] += __shfl_xor(dd[j], 1);
      dd[j] += __shfl_xor(dd[j], 2);
      dd[j] += __shfl_xor(dd[j], 4);
    }
    #pragma unroll
    for (int j = 0; j < 4; ++j) {
      const float p = __expf(dd[j]);
      s += p;
      float vv[8]; unpack8(V[j], vv);
      #pragma unroll
      for (int c = 0; c < 8; ++c) acc[c] = fmaf(p, vv[c], acc[c]);
    }
  }
  for (; e < e1; ++e) {
    const int sa = cidx[e];
    uint4 kk = *(const uint4*)&k[(size_t)sa * 64 + cb];
    uint4 vv4 = *(const uint4*)&v[(size_t)sa * 64 + cb];
    float kv[8]; unpack8(kk, kv);
    float d = 0.f;
    #pragma unroll
    for (int c = 0; c < 8; ++c) d = fmaf(qv[c], kv[c], d);
    d += __shfl_xor(d, 1);
    d += __shfl_xor(d, 2);
    d += __shfl_xor(d, 4);
    const float p = __expf(d);
    s += p;
    float vv[8]; unpack8(vv4, vv);
    #pragma unroll
    for (int c = 0; c < 8; ++c) acc[c] = fmaf(p, vv[c], acc[c]);
  }
  const float inv = (e1 > e0) ? 1.f / s : 0.f;
  const float* sp = &skip[(size_t)node * 64 + cb];
  float4 o0, o1;
  o0.x = fmaf(acc[0], inv, sp[0]); o0.y = fmaf(acc[1], inv, sp[1]);
  o0.z = fmaf(acc[2], inv, sp[2]); o0.w = fmaf(acc[3], inv, sp[3]);
  o1.x = fmaf(acc[4], inv, sp[4]); o1.y = fmaf(acc[5], inv, sp[5]);
  o1.z = fmaf(acc[6], inv, sp[6]); o1.w = fmaf(acc[7], inv, sp[7]);
  *(float4*)&out[(size_t)node * 64 + cb] = o0;
  *(float4*)&out[(size_t)node * 64 + cb + 4] = o1;
}

// ---------------------------------------------------------------- launch
extern "C" void kernel_launch(void* const* d_in, const int* in_sizes, int n_in,
                              void* d_out, int out_size, void* d_ws, size_t ws_size,
                              hipStream_t stream) {
  const float* x = (const float*)d_in[0];
  const int* ei = (const int*)d_in[1];
  const int* esrc = ei;
  const int* edst = ei + NE;
  const float* Wf[8] = {(const float*)d_in[2],  (const float*)d_in[4],
                        (const float*)d_in[6],  (const float*)d_in[8],
                        (const float*)d_in[10], (const float*)d_in[12],
                        (const float*)d_in[14], (const float*)d_in[16]};
  const float* Bf[8] = {(const float*)d_in[3],  (const float*)d_in[5],
                        (const float*)d_in[7],  (const float*)d_in[9],
                        (const float*)d_in[11], (const float*)d_in[13],
                        (const float*)d_in[15], (const float*)d_in[17]};
  float* out = (float*)d_out;

  char* p = (char*)d_ws;
  auto alloc = [&](size_t b) { char* r = p; p += (b + 255) & ~(size_t)255; return r; };
  unsigned short* q1 = (unsigned short*)alloc((size_t)NN * 128 * 2);
  unsigned short* k1 = (unsigned short*)alloc((size_t)NN * 128 * 2);
  unsigned short* v1 = (unsigned short*)alloc((size_t)NN * 128 * 2);
  float*          sk1 = (float*)alloc((size_t)NN * 128 * 4);
  unsigned short* hh = (unsigned short*)alloc((size_t)NN * 128 * 2);
  unsigned short* hl = (unsigned short*)alloc((size_t)NN * 128 * 2);
  unsigned short* q2 = (unsigned short*)alloc((size_t)NN * 64 * 2);
  unsigned short* k2 = (unsigned short*)alloc((size_t)NN * 64 * 2);
  unsigned short* v2 = (unsigned short*)alloc((size_t)NN * 64 * 2);
  float*          sk2 = (float*)alloc((size_t)NN * 64 * 4);
  unsigned short* wh[8];
  unsigned short* wl[8];
  for (int i = 0; i < 8; ++i) {
    const int dout = (i < 4) ? 128 : 64;
    wh[i] = (unsigned short*)alloc((size_t)128 * dout * 2);
    wl[i] = (unsigned short*)alloc((size_t)128 * dout * 2);
  }
  int* rowp = (int*)alloc((size_t)(NN + 1) * 4);
  int* cidx = (int*)alloc((size_t)NE * 4);
  int* gcnt = (int*)alloc((size_t)NB * 4);
  int* base = (int*)alloc((size_t)(NB + 1) * 4);
  int* cursor = (int*)alloc((size_t)NB * 4);
  int* gdcnt = (int*)alloc((size_t)DTOT * 4);
  int* perm = (int*)alloc((size_t)NN * 4);
  // pairs aliases hh: bktscat writes + bktcsr reads it BEFORE attn1 writes hh
  unsigned int* pairs = (unsigned int*)hh;

  // ---- W convert (transpose + hi/lo split) ----
  WConv8 wc;
  for (int i = 0; i < 8; ++i) wc.m[i] = {Wf[i], wh[i], wl[i], (i < 4) ? 128 : 64};
  wconv_k<<<8, 1024, 0, stream>>>(wc);

  // ---- CSR build (bucketed) ----
  hipMemsetAsync(gcnt, 0, NB * sizeof(int), stream);
  bktcnt_k<<<256, 256, 0, stream>>>(edst, gcnt);
  bktscan_k<<<1, 512, 0, stream>>>(gcnt, base, cursor);
  bktscat_k<<<256, 256, 0, stream>>>(esrc, edst, cursor, pairs);
  bktcsr_k<<<NB, 256, 0, stream>>>(pairs, base, rowp, cidx);

  // ---- degree-sorted node permutation (contention-free counting sort) ----
  dcnt_k<<<NB, 256, 0, stream>>>(rowp, gdcnt);
  dscan2_k<<<1, 1024, 0, stream>>>(gdcnt);
  dperm2_k<<<NB, 256, 0, stream>>>(rowp, gdcnt, perm);

  // ---- layer 1 ----
  GArgs g1;
  g1.m[0] = {wh[0], wl[0], Bf[0], nullptr, q1};
  g1.m[1] = {wh[1], wl[1], Bf[1], nullptr, k1};
  g1.m[2] = {wh[2], wl[2], Bf[2], nullptr, v1};
  g1.m[3] = {wh[3], wl[3], Bf[3], sk1, nullptr};
  gemm4_mfma<128, false><<<(NN + 127) / 128, 256, 0, stream>>>(x, nullptr, nullptr, NN, g1);
  attn1_k<<<(NN + 31) / 32, 256, 0, stream>>>(q1, k1, v1, sk1, rowp, cidx, perm, hh, hl);

  // ---- layer 2 ----
  GArgs g2;
  g2.m[0] = {wh[4], wl[4], Bf[4], nullptr, q2};
  g2.m[1] = {wh[5], wl[5], Bf[5], nullptr, k2};
  g2.m[2] = {wh[6], wl[6], Bf[6], nullptr, v2};
  g2.m[3] = {wh[7], wl[7], Bf[7], sk2, nullptr};
  gemm4_mfma<64, true><<<(NN + 127) / 128, 256, 0, stream>>>(nullptr, hh, hl, NN, g2);
  attn2_k<<<(NN + 31) / 32, 256, 0, stream>>>(q2, k2, v2, sk2, rowp, cidx, perm, out);
}

// Round 10
// 433.660 us; speedup vs baseline: 1.0952x; 1.0952x over previous
//
#include <hip/hip_runtime.h>
#include <math.h>

#define NN 100000
#define NPAD 100096     // 782 blocks x 128 rows; node buffers padded to this
#define NE 1600000
#define NB 391          // ceil(NN/256) buckets of 256 dst nodes
#define BKSH 8
#define EPB 6250        // NE / 256 blocks
#define CSTAGE 5120     // LDS staging entries in bktcsr (mean 4096, +16 sigma)
#define NDEG 64         // degree clamp for balance sort
#define DTOT (NDEG * NB)

typedef __attribute__((ext_vector_type(8))) short bf16x8;
typedef __attribute__((ext_vector_type(4))) float f32x4;

// ---------------------------------------------------------------- bf16 utils
__device__ __forceinline__ unsigned short f2bf(float x) {
  unsigned int u = __float_as_uint(x);
  u += 0x7fffu + ((u >> 16) & 1u);   // RNE
  return (unsigned short)(u >> 16);
}
__device__ __forceinline__ float bf2f(unsigned short b) {
  return __uint_as_float(((unsigned int)b) << 16);
}
__device__ __forceinline__ void unpack8(uint4 u, float* f) {
  f[0] = __uint_as_float(u.x << 16); f[1] = __uint_as_float(u.x & 0xffff0000u);
  f[2] = __uint_as_float(u.y << 16); f[3] = __uint_as_float(u.y & 0xffff0000u);
  f[4] = __uint_as_float(u.z << 16); f[5] = __uint_as_float(u.z & 0xffff0000u);
  f[6] = __uint_as_float(u.w << 16); f[7] = __uint_as_float(u.w & 0xffff0000u);
}
__device__ __forceinline__ void split8(const float* f, bf16x8& h8, bf16x8& l8) {
  union { bf16x8 v; unsigned short s[8]; } H, L;
  #pragma unroll
  for (int j = 0; j < 8; ++j) {
    const unsigned short hh = f2bf(f[j]);
    H.s[j] = hh;
    L.s[j] = f2bf(f[j] - bf2f(hh));
  }
  h8 = H.v; l8 = L.v;
}
__device__ __forceinline__ void gl_lds16(const void* g, void* lds) {
  __builtin_amdgcn_global_load_lds(
      (const __attribute__((address_space(1))) unsigned int*)g,
      (__attribute__((address_space(3))) unsigned int*)lds, 16, 0, 0);
}

// counted-vmcnt pipeline barriers. vmcnt counts INSTRUCTIONS PER WAVE and
// retires IN ORDER. Per stage each wave issues 4 global_load_lds; each lo
// epilogue issues exactly 32 stores (uniform via padded outputs).
// wait_s must retire pf(s): #ops-younger-than-pf(s) is 4 after a hi stage,
// 36 (32 stores + 4 pf) after a lo stage, 0 at the final stage.
#define PIPE_WAIT4  asm volatile("s_waitcnt vmcnt(4)\n\ts_barrier" ::: "memory")
#define PIPE_WAIT36 asm volatile("s_waitcnt vmcnt(36)\n\ts_barrier" ::: "memory")
#define PIPE_WAIT0  asm volatile("s_waitcnt vmcnt(0)\n\ts_barrier" ::: "memory")
#define PIPE_BAR    asm volatile("s_barrier" ::: "memory")
#define PIPE_FENCE  asm volatile("" ::: "memory")

// ---------------------------------------------------------------- CSR build (bucketed)
__global__ __launch_bounds__(256)
void bktcnt_k(const int* __restrict__ dst, int* __restrict__ gcnt) {
  __shared__ int cnt[NB];
  for (int i = threadIdx.x; i < NB; i += 256) cnt[i] = 0;
  __syncthreads();
  const int e0 = blockIdx.x * EPB;
  for (int e = e0 + threadIdx.x; e < e0 + EPB; e += 256)
    atomicAdd(&cnt[dst[e] >> BKSH], 1);
  __syncthreads();
  for (int i = threadIdx.x; i < NB; i += 256)
    if (cnt[i]) atomicAdd(&gcnt[i], cnt[i]);
}

__global__ void bktscan_k(const int* __restrict__ gcnt, int* __restrict__ base,
                          int* __restrict__ cursor) {
  __shared__ int sh[512];
  const int t = threadIdx.x;
  const int v = (t < NB) ? gcnt[t] : 0;
  sh[t] = v;
  __syncthreads();
  #pragma unroll
  for (int off = 1; off < 512; off <<= 1) {
    int nv = (t >= off) ? sh[t - off] : 0;
    __syncthreads();
    sh[t] += nv;
    __syncthreads();
  }
  const int excl = sh[t] - v;
  if (t < NB) { base[t] = excl; cursor[t] = excl; }
  if (t == NB - 1) base[NB] = excl + v;   // == NE
}

__global__ __launch_bounds__(256)
void bktscat_k(const int* __restrict__ src, const int* __restrict__ dst,
               int* __restrict__ cursor, unsigned int* __restrict__ pairs) {
  __shared__ int cnt[NB];
  __shared__ int bbase[NB];
  for (int i = threadIdx.x; i < NB; i += 256) cnt[i] = 0;
  __syncthreads();
  const int e0 = blockIdx.x * EPB;
  for (int e = e0 + threadIdx.x; e < e0 + EPB; e += 256)
    atomicAdd(&cnt[dst[e] >> BKSH], 1);
  __syncthreads();
  for (int i = threadIdx.x; i < NB; i += 256) {
    bbase[i] = cnt[i] ? atomicAdd(&cursor[i], cnt[i]) : 0;
    cnt[i] = 0;
  }
  __syncthreads();
  for (int e = e0 + threadIdx.x; e < e0 + EPB; e += 256) {
    const int d = dst[e];
    const int b = d >> BKSH;
    const int loc = atomicAdd(&cnt[b], 1);
    pairs[bbase[b] + loc] = ((unsigned)src[e] << BKSH) | (unsigned)(d & 255);
  }
}

__global__ __launch_bounds__(256)
void bktcsr_k(const unsigned int* __restrict__ pairs, const int* __restrict__ base,
              int* __restrict__ rowp, int* __restrict__ cidx) {
  __shared__ int cnt[256];
  __shared__ int sums[256];
  __shared__ int stage[CSTAGE];
  const int b = blockIdx.x, t = threadIdx.x;
  const int p0 = base[b], p1 = base[b + 1], bs = p1 - p0;
  const int n0 = b << BKSH;
  const int nloc = (NN - n0 < 256) ? (NN - n0) : 256;
  cnt[t] = 0;
  __syncthreads();
  for (int i = p0 + t; i < p1; i += 256)
    atomicAdd(&cnt[pairs[i] & 255], 1);
  __syncthreads();
  const int v = cnt[t];
  sums[t] = v;
  __syncthreads();
  #pragma unroll
  for (int off = 1; off < 256; off <<= 1) {
    int nv = (t >= off) ? sums[t - off] : 0;
    __syncthreads();
    sums[t] += nv;
    __syncthreads();
  }
  const int myexcl = sums[t] - v;
  if (t < nloc) rowp[n0 + t] = p0 + myexcl;
  if (b == 0 && t == 0) rowp[NN] = base[NB];
  __syncthreads();
  cnt[t] = myexcl;     // reuse as cursor
  __syncthreads();
  if (bs <= CSTAGE) {
    for (int i = p0 + t; i < p1; i += 256) {
      const unsigned pk = pairs[i];
      const int loc = atomicAdd(&cnt[pk & 255], 1);
      stage[loc] = (int)(pk >> BKSH);
    }
    __syncthreads();
    for (int i = t; i < bs; i += 256) cidx[p0 + i] = stage[i];
  } else {
    for (int i = p0 + t; i < p1; i += 256) {
      const unsigned pk = pairs[i];
      const int loc = atomicAdd(&cnt[pk & 255], 1);
      cidx[p0 + loc] = (int)(pk >> BKSH);
    }
  }
}

// ---------------------------------------------------------------- degree sort
__global__ __launch_bounds__(256)
void dcnt_k(const int* __restrict__ rowp, int* __restrict__ gdcnt) {
  __shared__ int h[NDEG];
  const int t = threadIdx.x, b = blockIdx.x;
  if (t < NDEG) h[t] = 0;
  __syncthreads();
  const int n = b * 256 + t;
  if (n < NN) {
    int d = rowp[n + 1] - rowp[n];
    if (d > NDEG - 1) d = NDEG - 1;
    atomicAdd(&h[d], 1);
  }
  __syncthreads();
  if (t < NDEG) gdcnt[t * NB + b] = h[t];
}

__global__ __launch_bounds__(1024)
void dscan2_k(int* __restrict__ g) {
  __shared__ int part[1024];
  const int t = threadIdx.x;
  constexpr int PER = (DTOT + 1023) / 1024;   // 25
  int vals[PER];
  const int base = t * PER;
  int sum = 0;
  #pragma unroll
  for (int i = 0; i < PER; ++i) {
    const int idx = base + i;
    const int v = (idx < DTOT) ? g[idx] : 0;
    vals[i] = sum;
    sum += v;
  }
  part[t] = sum;
  __syncthreads();
  #pragma unroll
  for (int off = 1; off < 1024; off <<= 1) {
    int nv = (t >= off) ? part[t - off] : 0;
    __syncthreads();
    part[t] += nv;
    __syncthreads();
  }
  const int excl = part[t] - sum;
  #pragma unroll
  for (int i = 0; i < PER; ++i) {
    const int idx = base + i;
    if (idx < DTOT) g[idx] = excl + vals[i];
  }
}

// LPT order: heaviest-degree nodes FIRST (reverse of ascending counting sort)
__global__ __launch_bounds__(256)
void dperm2_k(const int* __restrict__ rowp, const int* __restrict__ gdcnt,
              int* __restrict__ perm) {
  __shared__ int lcur[NDEG];
  const int t = threadIdx.x, b = blockIdx.x;
  if (t < NDEG) lcur[t] = 0;
  __syncthreads();
  const int n = b * 256 + t;
  if (n < NN) {
    int d = rowp[n + 1] - rowp[n];
    if (d > NDEG - 1) d = NDEG - 1;
    const int r = atomicAdd(&lcur[d], 1);   // LDS-only atomic
    perm[NN - 1 - (gdcnt[d * NB + b] + r)] = n;
  }
}

// ---------------------------------------------------------------- W convert
struct WConv { const float* src; unsigned short* hi; unsigned short* lo; int dout; };
struct WConv8 { WConv m[8]; };

__global__ void wconv_k(WConv8 a) {
  const WConv w = a.m[blockIdx.x];
  const int n = 128 * w.dout;
  for (int i = threadIdx.x; i < n; i += blockDim.x) {
    const int c = i >> 7, kk = i & 127;  // out idx = c*128 + kk
    const float x = w.src[(size_t)kk * w.dout + c];
    const unsigned short h = f2bf(x);
    w.hi[i] = h;
    w.lo[i] = f2bf(x - bf2f(h));
  }
}

// ---------------------------------------------------------------- GEMM x4 (MFMA)
// Counted-vmcnt double-buffer with EXACT per-wave instruction accounting:
// 4 pf/stage, 32 stores/lo-epilogue (uniform via padded outputs), biases
// hoisted to registers and fenced out of the pipeline region.
struct GMat { const unsigned short* wh; const unsigned short* wl;
              const float* bias; float* outf; unsigned short* outb; };
struct GArgs { GMat m[4]; };

template <int DOUT, bool PRESPLIT>
__global__ __launch_bounds__(256, 3)
void gemm4_mfma(const float* __restrict__ X,
                const unsigned short* __restrict__ Xh,
                const unsigned short* __restrict__ Xl,
                int nrows, GArgs ga) {
  constexpr int NCG = DOUT / 64;
  constexpr int NS = 4 * NCG * 2;
  __shared__ __align__(16) unsigned short Bs[2][8192];
  const int t = threadIdx.x;
  const int w = t >> 6, l = t & 63;
  const int lr = l & 15, lg = l >> 4;
  const int row0 = blockIdx.x * 128;

  // biases -> registers (statically indexed after full unroll)
  float bias_r[4][NCG][4];
  #pragma unroll
  for (int m = 0; m < 4; ++m)
    #pragma unroll
    for (int cg = 0; cg < NCG; ++cg)
      #pragma unroll
      for (int nf = 0; nf < 4; ++nf)
        bias_r[m][cg][nf] = ga.m[m].bias[cg * 64 + nf * 16 + lr];

  bf16x8 ah[2][4], al[2][4];
  #pragma unroll
  for (int rf = 0; rf < 2; ++rf) {
    const int r = row0 + w * 32 + rf * 16 + lr;
    if constexpr (!PRESPLIT) {
      const bool ok = r < nrows;            // X is external: mask OOB reads
      const float* xp = &X[(size_t)r * 128];
      #pragma unroll
      for (int ks = 0; ks < 4; ++ks) {
        float f[8];
        if (ok) {
          *(float4*)&f[0] = *(const float4*)&xp[ks * 32 + lg * 8];
          *(float4*)&f[4] = *(const float4*)&xp[ks * 32 + lg * 8 + 4];
        } else {
          #pragma unroll
          for (int j = 0; j < 8; ++j) f[j] = 0.f;
        }
        split8(f, ah[rf][ks], al[rf][ks]);
      }
    } else {
      // Xh/Xl padded to NPAD rows: unconditional loads
      #pragma unroll
      for (int ks = 0; ks < 4; ++ks) {
        ah[rf][ks] = *(const bf16x8*)&Xh[(size_t)r * 128 + ks * 32 + lg * 8];
        al[rf][ks] = *(const bf16x8*)&Xl[(size_t)r * 128 + ks * 32 + lg * 8];
      }
    }
  }
  // Pin: all bias/A loads issue BEFORE pf(0) (memory ops cannot cross).
  PIPE_FENCE;

  auto stage = [&](int buf, int s) {
    const int m = s / (NCG * 2);
    const int rem = s - m * (NCG * 2);
    const int cg = rem >> 1, pl = rem & 1;
    const char* gb = (const char*)((pl ? ga.m[m].wl : ga.m[m].wh) + cg * 64 * 128);
    char* lb = (char*)&Bs[buf][0];
    #pragma unroll
    for (int i = 0; i < 4; ++i) {
      const int seg = (w * 4 + i) << 10;
      const int o = seg + l * 16;
      const int osw = o ^ (((o >> 8) & 7) << 4);
      gl_lds16(gb + osw, lb + seg);
    }
  };

  f32x4 acc[4][2];
  stage(0, 0);          // pf(0): 4 vmem instructions per wave
  int cur = 0;
  const int sw = (lr & 7) << 4;
  #pragma unroll
  for (int s = 0; s < NS; ++s) {
    if (s + 1 < NS) stage(cur ^ 1, s + 1);   // pf(s+1): 4 ops
    // wait for pf(s): younger ops = compute(s-1) vmem + pf(s+1)
    if (s == NS - 1)                { PIPE_WAIT0; }
    else if (s >= 2 && !(s & 1))    { PIPE_WAIT36; }   // after lo epilogue
    else                            { PIPE_WAIT4;  }   // after hi / prologue
    const int m = s / (NCG * 2);
    const int rem = s - m * (NCG * 2);
    const int cg = rem >> 1, pl = rem & 1;
    const char* lbase = (const char*)&Bs[cur][0];
    if (pl == 0) {
      // hi plane: acc = Ah*Bh + Al*Bh   (no vmem issued)
      #pragma unroll
      for (int nf = 0; nf < 4; ++nf) {
        const char* lp = lbase + nf * 4096 + lr * 256;
        bf16x8 bq[4];
        #pragma unroll
        for (int ks = 0; ks < 4; ++ks)
          bq[ks] = *(const bf16x8*)(lp + (((ks * 64 + lg * 16) ^ sw)));
        f32x4 a0 = {0.f, 0.f, 0.f, 0.f}, a1 = a0;
        #pragma unroll
        for (int ks = 0; ks < 4; ++ks) {
          a0 = __builtin_amdgcn_mfma_f32_16x16x32_bf16(ah[0][ks], bq[ks], a0, 0, 0, 0);
          a1 = __builtin_amdgcn_mfma_f32_16x16x32_bf16(ah[1][ks], bq[ks], a1, 0, 0, 0);
        }
        #pragma unroll
        for (int ks = 0; ks < 4; ++ks) {
          a0 = __builtin_amdgcn_mfma_f32_16x16x32_bf16(al[0][ks], bq[ks], a0, 0, 0, 0);
          a1 = __builtin_amdgcn_mfma_f32_16x16x32_bf16(al[1][ks], bq[ks], a1, 0, 0, 0);
        }
        acc[nf][0] = a0; acc[nf][1] = a1;
      }
    } else {
      // lo plane: acc += Ah*Bl; epilogue (exactly 32 stores per thread)
      const GMat gm = ga.m[m];
      #pragma unroll
      for (int nf = 0; nf < 4; ++nf) {
        const char* lp = lbase + nf * 4096 + lr * 256;
        bf16x8 bq[4];
        #pragma unroll
        for (int ks = 0; ks < 4; ++ks)
          bq[ks] = *(const bf16x8*)(lp + (((ks * 64 + lg * 16) ^ sw)));
        f32x4 a0 = acc[nf][0], a1 = acc[nf][1];
        #pragma unroll
        for (int ks = 0; ks < 4; ++ks) {
          a0 = __builtin_amdgcn_mfma_f32_16x16x32_bf16(ah[0][ks], bq[ks], a0, 0, 0, 0);
          a1 = __builtin_amdgcn_mfma_f32_16x16x32_bf16(ah[1][ks], bq[ks], a1, 0, 0, 0);
        }
        const int col = cg * 64 + nf * 16 + lr;
        const float bb = bias_r[m][cg][nf];
        #pragma unroll
        for (int j = 0; j < 4; ++j) {
          const int r0 = row0 + w * 32 + lg * 4 + j;
          const int r1 = r0 + 16;
          if (gm.outb) {
            gm.outb[(size_t)r0 * DOUT + col] = f2bf(a0[j] + bb);
            gm.outb[(size_t)r1 * DOUT + col] = f2bf(a1[j] + bb);
          } else {
            gm.outf[(size_t)r0 * DOUT + col] = a0[j] + bb;
            gm.outf[(size_t)r1 * DOUT + col] = a1[j] + bb;
          }
        }
      }
    }
    if (s + 1 < NS) PIPE_BAR;   // close reads of Bs[cur] before pf(s+2) overwrites
    cur ^= 1;
  }
}

// ---------------------------------------------------------------- attention
// Layer 1: heads=8, C=16, concat. 8 lanes/node, 4-edge deep pipeline.
__global__ __launch_bounds__(256)
void attn1_k(const unsigned short* __restrict__ q, const unsigned short* __restrict__ k,
             const unsigned short* __restrict__ v, const float* __restrict__ skip,
             const int* __restrict__ rowp, const int* __restrict__ cidx,
             const int* __restrict__ perm,
             unsigned short* __restrict__ hhi, unsigned short* __restrict__ hlo) {
  const int idx = blockIdx.x * 32 + (threadIdx.x >> 3);
  if (idx >= NN) return;
  const int node = perm[idx];
  const int cb = (threadIdx.x & 7) * 16;
  float qv[16];
  {
    uint4 q0 = *(const uint4*)&q[(size_t)node * 128 + cb];
    uint4 q1 = *(const uint4*)&q[(size_t)node * 128 + cb + 8];
    unpack8(q0, qv); unpack8(q1, qv + 8);
    #pragma unroll
    for (int c = 0; c < 16; ++c) qv[c] *= 0.25f;  // 1/sqrt(16)
  }
  float s = 0.f, acc[16];
  #pragma unroll
  for (int c = 0; c < 16; ++c) acc[c] = 0.f;
  const int e0 = rowp[node], e1 = rowp[node + 1];
  int e = e0;
  for (; e + 3 < e1; e += 4) {
    int sidx[4];
    #pragma unroll
    for (int j = 0; j < 4; ++j) sidx[j] = cidx[e + j];
    uint4 K[4][2], V[4][2];
    #pragma unroll
    for (int j = 0; j < 4; ++j) {
      const size_t o = (size_t)sidx[j] * 128 + cb;
      K[j][0] = *(const uint4*)&k[o];
      K[j][1] = *(const uint4*)&k[o + 8];
      V[j][0] = *(const uint4*)&v[o];
      V[j][1] = *(const uint4*)&v[o + 8];
    }
    float pr[4];
    #pragma unroll
    for (int j = 0; j < 4; ++j) {
      float kv[16];
      unpack8(K[j][0], kv); unpack8(K[j][1], kv + 8);
      float d = 0.f;
      #pragma unroll
      for (int c = 0; c < 16; ++c) d = fmaf(qv[c], kv[c], d);
      pr[j] = __expf(d);
      s += pr[j];
    }
    #pragma unroll
    for (int j = 0; j < 4; ++j) {
      float vv[16];
      unpack8(V[j][0], vv); unpack8(V[j][1], vv + 8);
      #pragma unroll
      for (int c = 0; c < 16; ++c) acc[c] = fmaf(pr[j], vv[c], acc[c]);
    }
  }
  for (; e < e1; ++e) {
    const int sa = cidx[e];
    uint4 k0 = *(const uint4*)&k[(size_t)sa * 128 + cb];
    uint4 k1 = *(const uint4*)&k[(size_t)sa * 128 + cb + 8];
    uint4 v0 = *(const uint4*)&v[(size_t)sa * 128 + cb];
    uint4 v1 = *(const uint4*)&v[(size_t)sa * 128 + cb + 8];
    float kv[16]; unpack8(k0, kv); unpack8(k1, kv + 8);
    float d = 0.f;
    #pragma unroll
    for (int c = 0; c < 16; ++c) d = fmaf(qv[c], kv[c], d);
    const float p = __expf(d);
    s += p;
    float vv[16]; unpack8(v0, vv); unpack8(v1, vv + 8);
    #pragma unroll
    for (int c = 0; c < 16; ++c) acc[c] = fmaf(p, vv[c], acc[c]);
  }
  const float inv = (e1 > e0) ? 1.f / s : 0.f;
  float sk[16];
  {
    const float* sp = &skip[(size_t)node * 128 + cb];
    *(float4*)&sk[0]  = *(const float4*)&sp[0];
    *(float4*)&sk[4]  = *(const float4*)&sp[4];
    *(float4*)&sk[8]  = *(const float4*)&sp[8];
    *(float4*)&sk[12] = *(const float4*)&sp[12];
  }
  unsigned int hw[8], lw[8];
  #pragma unroll
  for (int c2 = 0; c2 < 8; ++c2) {
    const float oa = fmaxf(fmaf(acc[2 * c2], inv, sk[2 * c2]), 0.f);
    const float ob = fmaxf(fmaf(acc[2 * c2 + 1], inv, sk[2 * c2 + 1]), 0.f);
    const unsigned short ha = f2bf(oa), hb = f2bf(ob);
    hw[c2] = (unsigned)ha | ((unsigned)hb << 16);
    lw[c2] = (unsigned)f2bf(oa - bf2f(ha)) | ((unsigned)f2bf(ob - bf2f(hb)) << 16);
  }
  uint4* HH = (uint4*)&hhi[(size_t)node * 128 + cb];
  uint4* LL = (uint4*)&hlo[(size_t)node * 128 + cb];
  HH[0] = make_uint4(hw[0], hw[1], hw[2], hw[3]);
  HH[1] = make_uint4(hw[4], hw[5], hw[6], hw[7]);
  LL[0] = make_uint4(lw[0], lw[1], lw[2], lw[3]);
  LL[1] = make_uint4(lw[4], lw[5], lw[6], lw[7]);
}

// Layer 2: heads=1, C=64. 8 lanes/node, 4-edge deep pipeline.
__global__ __launch_bounds__(256)
void attn2_k(const unsigned short* __restrict__ q, const unsigned short* __restrict__ k,
             const unsigned short* __restrict__ v, const float* __restrict__ skip,
             const int* __restrict__ rowp, const int* __restrict__ cidx,
             const int* __restrict__ perm, float* __restrict__ out) {
  const int idx = blockIdx.x * 32 + (threadIdx.x >> 3);
  if (idx >= NN) return;
  const int node = perm[idx];
  const int cb = (threadIdx.x & 7) * 8;
  float qv[8];
  {
    uint4 q0 = *(const uint4*)&q[(size_t)node * 64 + cb];
    unpack8(q0, qv);
    #pragma unroll
    for (int c = 0; c < 8; ++c) qv[c] *= 0.125f;  // 1/sqrt(64)
  }
  float s = 0.f, acc[8];
  #pragma unroll
  for (int c = 0; c < 8; ++c) acc[c] = 0.f;
  const int e0 = rowp[node], e1 = rowp[node + 1];
  int e = e0;
  for (; e + 3 < e1; e += 4) {
    int sidx[4];
    #pragma unroll
    for (int j = 0; j < 4; ++j) sidx[j] = cidx[e + j];
    uint4 K[4], V[4];
    #pragma unroll
    for (int j = 0; j < 4; ++j) {
      const size_t o = (size_t)sidx[j] * 64 + cb;
      K[j] = *(const uint4*)&k[o];
      V[j] = *(const uint4*)&v[o];
    }
    float dd[4];
    #pragma unroll
    for (int j = 0; j < 4; ++j) {
      float kv[8]; unpack8(K[j], kv);
      float d = 0.f;
      #pragma unroll
      for (int c = 0; c < 8; ++c) d = fmaf(qv[c], kv[c], d);
      dd[j] = d;
    }
    #pragma unroll
    for (int j = 0; j < 4; ++j) {
      dd[j] += __shfl_xor(dd[j], 1);
      dd[j] += __shfl_xor(dd[j], 2);
      dd[j] += __shfl_xor(dd[j], 4);
    }
    #pragma unroll
    for (int j = 0; j < 4; ++j) {
      const float p = __expf(dd[j]);
      s += p;
      float vv[8]; unpack8(V[j], vv);
      #pragma unroll
      for (int c = 0; c < 8; ++c) acc[c] = fmaf(p, vv[c], acc[c]);
    }
  }
  for (; e < e1; ++e) {
    const int sa = cidx[e];
    uint4 kk = *(const uint4*)&k[(size_t)sa * 64 + cb];
    uint4 vv4 = *(const uint4*)&v[(size_t)sa * 64 + cb];
    float kv[8]; unpack8(kk, kv);
    float d = 0.f;
    #pragma unroll
    for (int c = 0; c < 8; ++c) d = fmaf(qv[c], kv[c], d);
    d += __shfl_xor(d, 1);
    d += __shfl_xor(d, 2);
    d += __shfl_xor(d, 4);
    const float p = __expf(d);
    s += p;
    float vv[8]; unpack8(vv4, vv);
    #pragma unroll
    for (int c = 0; c < 8; ++c) acc[c] = fmaf(p, vv[c], acc[c]);
  }
  const float inv = (e1 > e0) ? 1.f / s : 0.f;
  const float* sp = &skip[(size_t)node * 64 + cb];
  float4 o0, o1;
  o0.x = fmaf(acc[0], inv, sp[0]); o0.y = fmaf(acc[1], inv, sp[1]);
  o0.z = fmaf(acc[2], inv, sp[2]); o0.w = fmaf(acc[3], inv, sp[3]);
  o1.x = fmaf(acc[4], inv, sp[4]); o1.y = fmaf(acc[5], inv, sp[5]);
  o1.z = fmaf(acc[6], inv, sp[6]); o1.w = fmaf(acc[7], inv, sp[7]);
  *(float4*)&out[(size_t)node * 64 + cb] = o0;
  *(float4*)&out[(size_t)node * 64 + cb + 4] = o1;
}

// ---------------------------------------------------------------- launch
extern "C" void kernel_launch(void* const* d_in, const int* in_sizes, int n_in,
                              void* d_out, int out_size, void* d_ws, size_t ws_size,
                              hipStream_t stream) {
  const float* x = (const float*)d_in[0];
  const int* ei = (const int*)d_in[1];
  const int* esrc = ei;
  const int* edst = ei + NE;
  const float* Wf[8] = {(const float*)d_in[2],  (const float*)d_in[4],
                        (const float*)d_in[6],  (const float*)d_in[8],
                        (const float*)d_in[10], (const float*)d_in[12],
                        (const float*)d_in[14], (const float*)d_in[16]};
  const float* Bf[8] = {(const float*)d_in[3],  (const float*)d_in[5],
                        (const float*)d_in[7],  (const float*)d_in[9],
                        (const float*)d_in[11], (const float*)d_in[13],
                        (const float*)d_in[15], (const float*)d_in[17]};
  float* out = (float*)d_out;

  char* p = (char*)d_ws;
  auto alloc = [&](size_t b) { char* r = p; p += (b + 255) & ~(size_t)255; return r; };
  // node buffers padded to NPAD rows (uniform unconditional GEMM stores)
  unsigned short* q1 = (unsigned short*)alloc((size_t)NPAD * 128 * 2);
  unsigned short* k1 = (unsigned short*)alloc((size_t)NPAD * 128 * 2);
  unsigned short* v1 = (unsigned short*)alloc((size_t)NPAD * 128 * 2);
  float*          sk1 = (float*)alloc((size_t)NPAD * 128 * 4);
  unsigned short* hh = (unsigned short*)alloc((size_t)NPAD * 128 * 2);
  unsigned short* hl = (unsigned short*)alloc((size_t)NPAD * 128 * 2);
  unsigned short* q2 = (unsigned short*)alloc((size_t)NPAD * 64 * 2);
  unsigned short* k2 = (unsigned short*)alloc((size_t)NPAD * 64 * 2);
  unsigned short* v2 = (unsigned short*)alloc((size_t)NPAD * 64 * 2);
  float*          sk2 = (float*)alloc((size_t)NPAD * 64 * 4);
  unsigned short* wh[8];
  unsigned short* wl[8];
  for (int i = 0; i < 8; ++i) {
    const int dout = (i < 4) ? 128 : 64;
    wh[i] = (unsigned short*)alloc((size_t)128 * dout * 2);
    wl[i] = (unsigned short*)alloc((size_t)128 * dout * 2);
  }
  int* rowp = (int*)alloc((size_t)(NN + 1) * 4);
  int* cidx = (int*)alloc((size_t)NE * 4);
  int* gcnt = (int*)alloc((size_t)NB * 4);
  int* base = (int*)alloc((size_t)(NB + 1) * 4);
  int* cursor = (int*)alloc((size_t)NB * 4);
  int* gdcnt = (int*)alloc((size_t)DTOT * 4);
  int* perm = (int*)alloc((size_t)NN * 4);
  // pairs aliases hh: bktscat writes + bktcsr reads it BEFORE attn1 writes hh
  unsigned int* pairs = (unsigned int*)hh;

  // ---- W convert (transpose + hi/lo split) ----
  WConv8 wc;
  for (int i = 0; i < 8; ++i) wc.m[i] = {Wf[i], wh[i], wl[i], (i < 4) ? 128 : 64};
  wconv_k<<<8, 1024, 0, stream>>>(wc);

  // ---- CSR build (bucketed) ----
  hipMemsetAsync(gcnt, 0, NB * sizeof(int), stream);
  bktcnt_k<<<256, 256, 0, stream>>>(edst, gcnt);
  bktscan_k<<<1, 512, 0, stream>>>(gcnt, base, cursor);
  bktscat_k<<<256, 256, 0, stream>>>(esrc, edst, cursor, pairs);
  bktcsr_k<<<NB, 256, 0, stream>>>(pairs, base, rowp, cidx);

  // ---- degree-sorted node permutation (contention-free, LPT order) ----
  dcnt_k<<<NB, 256, 0, stream>>>(rowp, gdcnt);
  dscan2_k<<<1, 1024, 0, stream>>>(gdcnt);
  dperm2_k<<<NB, 256, 0, stream>>>(rowp, gdcnt, perm);

  // ---- layer 1 ----
  GArgs g1;
  g1.m[0] = {wh[0], wl[0], Bf[0], nullptr, q1};
  g1.m[1] = {wh[1], wl[1], Bf[1], nullptr, k1};
  g1.m[2] = {wh[2], wl[2], Bf[2], nullptr, v1};
  g1.m[3] = {wh[3], wl[3], Bf[3], sk1, nullptr};
  gemm4_mfma<128, false><<<NPAD / 128, 256, 0, stream>>>(x, nullptr, nullptr, NN, g1);
  attn1_k<<<(NN + 31) / 32, 256, 0, stream>>>(q1, k1, v1, sk1, rowp, cidx, perm, hh, hl);

  // ---- layer 2 ----
  GArgs g2;
  g2.m[0] = {wh[4], wl[4], Bf[4], nullptr, q2};
  g2.m[1] = {wh[5], wl[5], Bf[5], nullptr, k2};
  g2.m[2] = {wh[6], wl[6], Bf[6], nullptr, v2};
  g2.m[3] = {wh[7], wl[7], Bf[7], sk2, nullptr};
  gemm4_mfma<64, true><<<NPAD / 128, 256, 0, stream>>>(nullptr, hh, hl, NN, g2);
  attn2_k<<<(NN + 31) / 32, 256, 0, stream>>>(q2, k2, v2, sk2, rowp, cidx, perm, out);
}